// Round 2
// baseline (92.427 us; speedup 1.0000x reference)
//
#include <hip/hip_runtime.h>

// x (8192,64) f32, x_var (8192,64) f32, proto_mean (19,10,64) f32,
// proto_var (19,10,64) f32  ->  out (8192,19,10) f32.
//
// out[n,cm] = -1/128 * ( sum_k (pm-x)^2/(xv+pv)  +  ln prod_k (xv+pv) )
//
// Structure: 1 wave per block; lane <-> row; each lane keeps its full
// x/xv row (2x64 floats) in VGPRs and loops over 10 cm's. pm/pv addresses
// are wave-uniform -> scalar loads (broadcast, zero LDS). No LDS at all:
// round 1 was LDS-issue-bound (~44 us of ds_read issue by count model).
#define NROWS 8192
#define KDIM  64
#define CMDIM 190
#define CMT   10      // cm per wave
#define NCT   19      // cm tiles (grid.x)

__global__ __launch_bounds__(64)
void probproto_kernel(const float* __restrict__ x,
                      const float* __restrict__ xv,
                      const float* __restrict__ pm,
                      const float* __restrict__ pv,
                      float* __restrict__ out)
{
    const int lane = threadIdx.x;
    const int ct   = blockIdx.x;                 // 0..18, fast-varying -> row-tile shared by consecutive blocks
    const int n    = blockIdx.y * 64 + lane;     // global row

    // ---- load this lane's row of x and x_var into registers (128 VGPRs) ----
    float xr[KDIM], vr[KDIM];
    const float4* xp = (const float4*)(x  + (size_t)n * KDIM);
    const float4* vp = (const float4*)(xv + (size_t)n * KDIM);
    #pragma unroll
    for (int i = 0; i < KDIM / 4; ++i) {
        float4 a = xp[i], b = vp[i];
        xr[4*i+0] = a.x; xr[4*i+1] = a.y; xr[4*i+2] = a.z; xr[4*i+3] = a.w;
        vr[4*i+0] = b.x; vr[4*i+1] = b.y; vr[4*i+2] = b.z; vr[4*i+3] = b.w;
    }

    float* orow = out + (size_t)n * CMDIM + ct * CMT;

    // j-loop rolled (keeps code size ~one k-unrolled body in I-cache)
    for (int j = 0; j < CMT; ++j) {
        const float* pmr = pm + (size_t)(ct * CMT + j) * KDIM;  // wave-uniform -> s_load
        const float* pvr = pv + (size_t)(ct * CMT + j) * KDIM;

        float q[4] = {0.f, 0.f, 0.f, 0.f};   // 4-way ILP on the d^2/v accumulation
        float accL = 0.f;                    // sum of log2 over chunked products
        #pragma unroll
        for (int kc = 0; kc < 4; ++kc) {
            float p[4] = {1.f, 1.f, 1.f, 1.f};  // 4 product chains, 4 muls deep
            #pragma unroll
            for (int k8 = 0; k8 < 16; ++k8) {
                int k = kc * 16 + k8;
                float v = vr[k] + pvr[k];
                float d = pmr[k] - xr[k];
                q[k8 & 3] = fmaf(d * d, __builtin_amdgcn_rcpf(v), q[k8 & 3]);
                p[k8 & 3] *= v;              // v in [1,2): 16-element chunk < 2^16
            }
            accL += __log2f((p[0] * p[1]) * (p[2] * p[3]));  // 1 log per 16 k
        }
        // -0.5 * mean_K: -(sumQ + ln2 * accL) / 128
        orow[j] = -(((q[0] + q[1]) + (q[2] + q[3]))
                    + 0.69314718055994531f * accL) * (1.0f / 128.0f);
    }
}

extern "C" void kernel_launch(void* const* d_in, const int* in_sizes, int n_in,
                              void* d_out, int out_size, void* d_ws, size_t ws_size,
                              hipStream_t stream) {
    const float* x  = (const float*)d_in[0];
    const float* xv = (const float*)d_in[1];
    const float* pm = (const float*)d_in[2];
    const float* pv = (const float*)d_in[3];
    float* out = (float*)d_out;

    dim3 grid(NCT, NROWS / 64);   // 19 x 128 one-wave blocks
    probproto_kernel<<<grid, 64, 0, stream>>>(x, xv, pm, pv, out);
}